// Round 1
// baseline (1219.990 us; speedup 1.0000x reference)
//
#include <hip/hip_runtime.h>
#include <stdint.h>

typedef unsigned short u16;
typedef short bf16x8 __attribute__((ext_vector_type(8)));
typedef float f32x4 __attribute__((ext_vector_type(4)));

#define CDIM 256
#define MSZ 65536  // 256*256

__device__ __forceinline__ u16 f2bf(float f) {
  union { float f; uint32_t u; } a; a.f = f;
  uint32_t u = a.u;
  uint32_t r = u + 0x7FFFu + ((u >> 16) & 1u);
  return (u16)(r >> 16);
}

// ---------------- transpose: At[m] = A[m]^T ----------------
__global__ void transpose_k(const float* __restrict__ A, float* __restrict__ At) {
  __shared__ float t[32][33];
  int m = blockIdx.y;
  int i0 = (blockIdx.x >> 3) * 32, j0 = (blockIdx.x & 7) * 32;
  int tid = threadIdx.x;
  const float* Am = A + (size_t)m * MSZ;
  float* Atm = At + (size_t)m * MSZ;
  for (int p = 0; p < 4; p++) {
    int e = tid + p * 256; int ii = e >> 5, jj = e & 31;
    t[ii][jj] = Am[(i0 + ii) * CDIM + j0 + jj];
  }
  __syncthreads();
  for (int p = 0; p < 4; p++) {
    int e = tid + p * 256; int jj = e >> 5, ii = e & 31;
    Atm[(j0 + jj) * CDIM + i0 + ii] = t[ii][jj];
  }
}

// ---------------- power iteration: s = sigma_max, w0 = A/s ----------------
__global__ void power_k(const float* __restrict__ A, const float* __restrict__ At,
                        const float* __restrict__ u0, float* __restrict__ w0,
                        float* __restrict__ sval) {
  int m = blockIdx.x; int t = threadIdx.x;
  __shared__ float u[CDIM], v[CDIM], red[4];
  const float* Am = A + (size_t)m * MSZ;
  const float* Atm = At + (size_t)m * MSZ;
  u[t] = u0[m * CDIM + t];
  __syncthreads();
  float nu = 1.0f;
  for (int it = 0; it < 10; ++it) {
    // v = A^T u  (thread t = column t, coalesced)
    float acc = 0.f;
    #pragma unroll 4
    for (int i = 0; i < CDIM; i++) acc += Am[i * CDIM + t] * u[i];
    float ss = acc * acc;
    for (int off = 32; off; off >>= 1) ss += __shfl_down(ss, off);
    __syncthreads();
    if ((t & 63) == 0) red[t >> 6] = ss;
    __syncthreads();
    float nv = sqrtf(red[0] + red[1] + red[2] + red[3]);
    v[t] = acc / nv;
    __syncthreads();
    // u = A v  via At (thread t = row t, coalesced)
    float acc2 = 0.f;
    #pragma unroll 4
    for (int j = 0; j < CDIM; j++) acc2 += Atm[j * CDIM + t] * v[j];
    float s2 = acc2 * acc2;
    for (int off = 32; off; off >>= 1) s2 += __shfl_down(s2, off);
    __syncthreads();
    if ((t & 63) == 0) red[t >> 6] = s2;
    __syncthreads();
    nu = sqrtf(red[0] + red[1] + red[2] + red[3]);
    u[t] = acc2 / nu;
    __syncthreads();
  }
  // s = u^T A v = ||A v|| = nu (exactly, since u = Av/||Av||)
  float inv = 1.0f / nu;
  for (int e = t; e < MSZ; e += CDIM) w0[(size_t)m * MSZ + e] = Am[e] * inv;
  if (t == 0) sval[m] = nu;
}

// ---------------- Bjorck: T = W^T W ----------------
__global__ void wtw_k(const float* __restrict__ W, float* __restrict__ T) {
  int m = blockIdx.y;
  int i0 = (blockIdx.x >> 3) * 32, j0 = (blockIdx.x & 7) * 32;
  const float* A = W + (size_t)m * MSZ;
  __shared__ float As[32][33], Bs[32][33];
  int tid = threadIdx.x, tx = tid & 15, ty = tid >> 4;
  float a00 = 0, a01 = 0, a10 = 0, a11 = 0;
  for (int kc = 0; kc < CDIM; kc += 32) {
    __syncthreads();
    for (int p = 0; p < 4; p++) {
      int e = tid + p * 256; int kk = e >> 5, cc = e & 31;
      As[kk][cc] = A[(kc + kk) * CDIM + i0 + cc];
      Bs[kk][cc] = A[(kc + kk) * CDIM + j0 + cc];
    }
    __syncthreads();
    #pragma unroll
    for (int kk = 0; kk < 32; kk++) {
      float av0 = As[kk][ty], av1 = As[kk][ty + 16];
      float bv0 = Bs[kk][tx], bv1 = Bs[kk][tx + 16];
      a00 += av0 * bv0; a01 += av0 * bv1; a10 += av1 * bv0; a11 += av1 * bv1;
    }
  }
  float* Tm = T + (size_t)m * MSZ;
  Tm[(i0 + ty) * CDIM + j0 + tx] = a00;
  Tm[(i0 + ty) * CDIM + j0 + tx + 16] = a01;
  Tm[(i0 + ty + 16) * CDIM + j0 + tx] = a10;
  Tm[(i0 + ty + 16) * CDIM + j0 + tx + 16] = a11;
}

// ---------------- Bjorck: Wn = 1.5 W - 0.5 W*T ----------------
__global__ void update_k(const float* __restrict__ W, const float* __restrict__ T,
                         float* __restrict__ Wn) {
  int m = blockIdx.y;
  int i0 = (blockIdx.x >> 3) * 32, j0 = (blockIdx.x & 7) * 32;
  const float* A = W + (size_t)m * MSZ;
  const float* B = T + (size_t)m * MSZ;
  __shared__ float As[32][33], Bs[32][33];
  int tid = threadIdx.x, tx = tid & 15, ty = tid >> 4;
  float a00 = 0, a01 = 0, a10 = 0, a11 = 0;
  for (int kc = 0; kc < CDIM; kc += 32) {
    __syncthreads();
    for (int p = 0; p < 4; p++) {
      int e = tid + p * 256; int r = e >> 5, c2 = e & 31;
      As[r][c2] = A[(i0 + r) * CDIM + kc + c2];
      Bs[r][c2] = B[(kc + r) * CDIM + j0 + c2];
    }
    __syncthreads();
    #pragma unroll
    for (int kk = 0; kk < 32; kk++) {
      float av0 = As[ty][kk], av1 = As[ty + 16][kk];
      float bv0 = Bs[kk][tx], bv1 = Bs[kk][tx + 16];
      a00 += av0 * bv0; a01 += av0 * bv1; a10 += av1 * bv0; a11 += av1 * bv1;
    }
  }
  float* Wm = Wn + (size_t)m * MSZ;
  Wm[(i0 + ty) * CDIM + j0 + tx]           = 1.5f * A[(i0 + ty) * CDIM + j0 + tx] - 0.5f * a00;
  Wm[(i0 + ty) * CDIM + j0 + tx + 16]      = 1.5f * A[(i0 + ty) * CDIM + j0 + tx + 16] - 0.5f * a01;
  Wm[(i0 + ty + 16) * CDIM + j0 + tx]      = 1.5f * A[(i0 + ty + 16) * CDIM + j0 + tx] - 0.5f * a10;
  Wm[(i0 + ty + 16) * CDIM + j0 + tx + 16] = 1.5f * A[(i0 + ty + 16) * CDIM + j0 + tx + 16] - 0.5f * a11;
}

// ---------------- PQ[t] = masked(O[1+t]) @ masked(O[1+t])^T  (K=128) ----------------
__global__ void pq_k(const float* __restrict__ O, float* __restrict__ PQ) {
  int m = blockIdx.y;  // 0..3 -> matrix 1+m
  const float* A = O + (size_t)(1 + m) * MSZ;
  int i0 = (blockIdx.x >> 3) * 32, j0 = (blockIdx.x & 7) * 32;
  __shared__ float As[32][33], Bs[32][33];
  int tid = threadIdx.x, tx = tid & 15, ty = tid >> 4;
  float a00 = 0, a01 = 0, a10 = 0, a11 = 0;
  for (int kc = 0; kc < 128; kc += 32) {   // mask: only first 128 columns
    __syncthreads();
    for (int p = 0; p < 4; p++) {
      int e = tid + p * 256; int r = e >> 5, c2 = e & 31;
      As[r][c2] = A[(i0 + r) * CDIM + kc + c2];
      Bs[r][c2] = A[(j0 + r) * CDIM + kc + c2];
    }
    __syncthreads();
    #pragma unroll
    for (int kk = 0; kk < 32; kk++) {
      float av0 = As[ty][kk], av1 = As[ty + 16][kk];
      float bv0 = Bs[tx][kk], bv1 = Bs[tx + 16][kk];
      a00 += av0 * bv0; a01 += av0 * bv1; a10 += av1 * bv0; a11 += av1 * bv1;
    }
  }
  float* out = PQ + (size_t)m * MSZ;
  out[(i0 + ty) * CDIM + j0 + tx] = a00;
  out[(i0 + ty) * CDIM + j0 + tx + 16] = a01;
  out[(i0 + ty + 16) * CDIM + j0 + tx] = a10;
  out[(i0 + ty + 16) * CDIM + j0 + tx + 16] = a11;
}

// ---------------- C1 = PQ0@PQ1 ; C2 = PQ2@PQ3 ----------------
__global__ void c12_k(const float* __restrict__ PQ, float* __restrict__ C12) {
  int z = blockIdx.y;
  const float* A = PQ + (size_t)(2 * z) * MSZ;
  const float* B = PQ + (size_t)(2 * z + 1) * MSZ;
  int i0 = (blockIdx.x >> 3) * 32, j0 = (blockIdx.x & 7) * 32;
  __shared__ float As[32][33], Bs[32][33];
  int tid = threadIdx.x, tx = tid & 15, ty = tid >> 4;
  float a00 = 0, a01 = 0, a10 = 0, a11 = 0;
  for (int kc = 0; kc < CDIM; kc += 32) {
    __syncthreads();
    for (int p = 0; p < 4; p++) {
      int e = tid + p * 256; int r = e >> 5, c2 = e & 31;
      As[r][c2] = A[(i0 + r) * CDIM + kc + c2];
      Bs[r][c2] = B[(kc + r) * CDIM + j0 + c2];
    }
    __syncthreads();
    #pragma unroll
    for (int kk = 0; kk < 32; kk++) {
      float av0 = As[ty][kk], av1 = As[ty + 16][kk];
      float bv0 = Bs[kk][tx], bv1 = Bs[kk][tx + 16];
      a00 += av0 * bv0; a01 += av0 * bv1; a10 += av1 * bv0; a11 += av1 * bv1;
    }
  }
  float* out = C12 + (size_t)z * MSZ;
  out[(i0 + ty) * CDIM + j0 + tx] = a00;
  out[(i0 + ty) * CDIM + j0 + tx + 16] = a01;
  out[(i0 + ty + 16) * CDIM + j0 + tx] = a10;
  out[(i0 + ty + 16) * CDIM + j0 + tx + 16] = a11;
}

// ---------------- build 2x2 block-orth members ----------------
__global__ void blocks_k(const float* __restrict__ PQ, const float* __restrict__ C12,
                         float* __restrict__ P, float* __restrict__ Q) {
  int idx = blockIdx.x * 256 + threadIdx.x;
  int row = idx >> 8, col = idx & 255;
  float I = (row == col) ? 1.f : 0.f;
  float p0 = PQ[idx], p1 = PQ[MSZ + idx], c1 = C12[idx];
  P[idx] = c1;                       // p00 = p1@p2
  P[MSZ + idx] = p0 - c1;            // p01 = p1(I-p2)
  P[2 * MSZ + idx] = p1 - c1;        // p10 = (I-p1)p2
  P[3 * MSZ + idx] = I - p0 - p1 + c1;
  float q0 = PQ[2 * MSZ + idx], q1 = PQ[3 * MSZ + idx], c2 = C12[MSZ + idx];
  Q[idx] = c2;
  Q[MSZ + idx] = q0 - c2;
  Q[2 * MSZ + idx] = q1 - c2;
  Q[3 * MSZ + idx] = I - q0 - q1 + c2;
}

// ---------------- matrix_conv: R[ij] = sum_t P[tp]@Q[tq] ----------------
__global__ void mconv_k(const float* __restrict__ P, const float* __restrict__ Q,
                        float* __restrict__ R) {
  int ij = blockIdx.y;
  int i0 = (blockIdx.x >> 3) * 32, j0 = (blockIdx.x & 7) * 32;
  const int toff[10] = {0, 1, 3, 4, 6, 10, 12, 13, 15, 16};
  const int tp[16] = {0, 0, 1, 1, 0, 2, 0, 1, 2, 3, 1, 3, 2, 2, 3, 3};
  const int tq[16] = {0, 1, 0, 1, 2, 0, 3, 2, 1, 0, 3, 1, 2, 3, 2, 3};
  __shared__ float As[32][33], Bs[32][33];
  int tid = threadIdx.x, tx = tid & 15, ty = tid >> 4;
  float a00 = 0, a01 = 0, a10 = 0, a11 = 0;
  for (int t = toff[ij]; t < toff[ij + 1]; ++t) {
    const float* A = P + (size_t)tp[t] * MSZ;
    const float* B = Q + (size_t)tq[t] * MSZ;
    for (int kc = 0; kc < CDIM; kc += 32) {
      __syncthreads();
      for (int p = 0; p < 4; p++) {
        int e = tid + p * 256; int r = e >> 5, c2 = e & 31;
        As[r][c2] = A[(i0 + r) * CDIM + kc + c2];
        Bs[r][c2] = B[(kc + r) * CDIM + j0 + c2];
      }
      __syncthreads();
      #pragma unroll
      for (int kk = 0; kk < 32; kk++) {
        float av0 = As[ty][kk], av1 = As[ty + 16][kk];
        float bv0 = Bs[kk][tx], bv1 = Bs[kk][tx + 16];
        a00 += av0 * bv0; a01 += av0 * bv1; a10 += av1 * bv0; a11 += av1 * bv1;
      }
    }
  }
  float* out = R + (size_t)ij * MSZ;
  out[(i0 + ty) * CDIM + j0 + tx] = a00;
  out[(i0 + ty) * CDIM + j0 + tx + 16] = a01;
  out[(i0 + ty + 16) * CDIM + j0 + tx] = a10;
  out[(i0 + ty + 16) * CDIM + j0 + tx + 16] = a11;
}

// ---------------- final: Wb[ij][cout][cin] = bf16( (H @ R[ij])^T ) ----------------
__global__ void final_k(const float* __restrict__ H, const float* __restrict__ R,
                        u16* __restrict__ Wb) {
  int ij = blockIdx.y;
  const float* B = R + (size_t)ij * MSZ;
  int i0 = (blockIdx.x >> 3) * 32, j0 = (blockIdx.x & 7) * 32;
  __shared__ float As[32][33], Bs[32][33];
  int tid = threadIdx.x, tx = tid & 15, ty = tid >> 4;
  float a00 = 0, a01 = 0, a10 = 0, a11 = 0;
  for (int kc = 0; kc < CDIM; kc += 32) {
    __syncthreads();
    for (int p = 0; p < 4; p++) {
      int e = tid + p * 256; int r = e >> 5, c2 = e & 31;
      As[r][c2] = H[(i0 + r) * CDIM + kc + c2];
      Bs[r][c2] = B[(kc + r) * CDIM + j0 + c2];
    }
    __syncthreads();
    #pragma unroll
    for (int kk = 0; kk < 32; kk++) {
      float av0 = As[ty][kk], av1 = As[ty + 16][kk];
      float bv0 = Bs[kk][tx], bv1 = Bs[kk][tx + 16];
      a00 += av0 * bv0; a01 += av0 * bv1; a10 += av1 * bv0; a11 += av1 * bv1;
    }
  }
  // store transposed: row (i0+ty) = cin, col (j0+tx) = cout -> Wb[ij][cout][cin]
  u16* Wm = Wb + (size_t)ij * MSZ;
  Wm[(j0 + tx) * CDIM + (i0 + ty)] = f2bf(a00);
  Wm[(j0 + tx + 16) * CDIM + (i0 + ty)] = f2bf(a01);
  Wm[(j0 + tx) * CDIM + (i0 + ty + 16)] = f2bf(a10);
  Wm[(j0 + tx + 16) * CDIM + (i0 + ty + 16)] = f2bf(a11);
}

// ---------------- x: NCHW f32 -> NHWC bf16 ----------------
__global__ void convert_k(const float* __restrict__ x, u16* __restrict__ xb) {
  __shared__ float t[32][33];
  int b = blockIdx.x;
  int ctile = b & 7, wtile = (b >> 3) & 1, h = (b >> 4) & 63, n = b >> 10;
  int c0 = ctile * 32, w0 = wtile * 32;
  int tid = threadIdx.x;
  for (int p = 0; p < 4; p++) {
    int e = tid + p * 256; int cc = e >> 5, ww = e & 31;
    t[cc][ww] = x[(((size_t)n * 256 + c0 + cc) * 64 + h) * 64 + w0 + ww];
  }
  __syncthreads();
  for (int p = 0; p < 4; p++) {
    int e = tid + p * 256; int ww = e >> 5, cc = e & 31;
    xb[(((size_t)n * 64 + h) * 64 + w0 + ww) * 256 + c0 + cc] = f2bf(t[cc][ww]);
  }
}

// ---------------- the conv: implicit GEMM, MFMA bf16 ----------------
// grid: b = ((n*32 + ht)*2 + bn), 256 threads (4 waves)
// block tile: 128 pos (2 rows x 64 w) x 128 cout; K = cin(256, 4 tiles of 64) x 9 taps
__global__ void conv_k(const u16* __restrict__ xb, const u16* __restrict__ Wb,
                       const float* __restrict__ bias, float* __restrict__ out) {
  int b = blockIdx.x;
  int bn = b & 1;
  int ht = (b >> 1) & 31;
  int n = b >> 6;
  int h0 = ht * 2;
  int tid = threadIdx.x;
  int lane = tid & 63, wave = tid >> 6;
  int wm = wave >> 1, wn = wave & 1;

  __shared__ uint4 smemv[3072];  // 48KB
  char* sX = (char*)smemv;        // 32KB: Xs[r4][w64][c64] bf16, swizzled
  char* sB = (char*)smemv + 32768;  // 16KB: Bt[cl128][cin64] bf16, swizzled

  f32x4 acc[4][4] = {};

  for (int ct = 0; ct < 4; ++ct) {
    __syncthreads();  // previous-iteration compute fully done
    // stage X block: rows h0-1..h0+2 (wrap), all 64 w, 64 cin
    for (int p = 0; p < 8; p++) {
      int e = tid + p * 256;          // 16B chunk id, 0..2047
      int cb = (e & 7) * 16;          // byte offset within 128B row
      int w = (e >> 3) & 63;
      int r = e >> 9;
      int hs = (h0 - 1 + r) & 63;
      const char* src = (const char*)xb + (((size_t)(n * 64 + hs) * 64 + w) * 512) + ct * 128 + cb;
      uint4 val = *(const uint4*)src;
      *(uint4*)(sX + (r * 64 + w) * 128 + (cb ^ ((w & 7) << 4))) = val;
    }
    for (int khw = 0; khw < 9; ++khw) {
      int kh = khw % 3, kw = khw / 3;
      if (khw) __syncthreads();  // previous Bs compute done
      {
        int ij = kw * 3 + kh;
        for (int p = 0; p < 4; p++) {
          int e = tid + p * 256;      // 0..1023
          int cb = (e & 7) * 16;
          int cl = e >> 3;            // cout_local 0..127
          const char* src = (const char*)Wb + ((size_t)(ij * 256 + bn * 128 + cl) * 512) + ct * 128 + cb;
          uint4 val = *(const uint4*)src;
          *(uint4*)(sB + cl * 128 + (cb ^ ((cl & 7) << 4))) = val;
        }
      }
      __syncthreads();
      #pragma unroll
      for (int ks = 0; ks < 2; ++ks) {
        bf16x8 af[4], bfr[4];
        int kbyte = ks * 64 + (lane >> 4) * 16;
        #pragma unroll
        for (int fm = 0; fm < 4; ++fm) {
          int wsrc = (fm * 16 + (lane & 15) + kw + 63) & 63;  // (w + kw - 1) mod 64
          af[fm] = *(const bf16x8*)(sX + ((wm + kh) * 64 + wsrc) * 128 + (kbyte ^ ((wsrc & 7) << 4)));
        }
        #pragma unroll
        for (int fn = 0; fn < 4; ++fn) {
          int cl = wn * 64 + fn * 16 + (lane & 15);
          bfr[fn] = *(const bf16x8*)(sB + cl * 128 + (kbyte ^ ((cl & 7) << 4)));
        }
        #pragma unroll
        for (int fm = 0; fm < 4; ++fm)
          #pragma unroll
          for (int fn = 0; fn < 4; ++fn)
            acc[fm][fn] = __builtin_amdgcn_mfma_f32_16x16x32_bf16(af[fm], bfr[fn], acc[fm][fn], 0, 0, 0);
      }
    }
  }
  // epilogue: D mapping col=lane&15 (cout), row=(lane>>4)*4+v (pos)
  int h = h0 + wm;
  #pragma unroll
  for (int fn = 0; fn < 4; ++fn) {
    int cg = bn * 128 + wn * 64 + fn * 16 + (lane & 15);
    float bv = bias[cg];
    #pragma unroll
    for (int fm = 0; fm < 4; ++fm) {
      int wbase = fm * 16 + (lane >> 4) * 4;
      f32x4 v = acc[fm][fn];
      v[0] += bv; v[1] += bv; v[2] += bv; v[3] += bv;
      *(f32x4*)(out + (((size_t)n * 256 + cg) * 64 + h) * 64 + wbase) = v;
    }
  }
}

extern "C" void kernel_launch(void* const* d_in, const int* in_sizes, int n_in,
                              void* d_out, int out_size, void* d_ws, size_t ws_size,
                              hipStream_t stream) {
  const float* x = (const float*)d_in[0];
  const float* param = (const float*)d_in[1];
  const float* u0 = (const float*)d_in[2];
  const float* bias = (const float*)d_in[3];
  float* out = (float*)d_out;

  char* ws = (char*)d_ws;
  size_t off = 0;
  auto alloc = [&](size_t bytes) -> void* {
    void* p = ws + off;
    off = (off + bytes + 255) & ~(size_t)255;
    return p;
  };
  u16* xb = (u16*)alloc((size_t)33554432 * 2);   // x bf16 NHWC, 64MB
  u16* Wb = (u16*)alloc((size_t)9 * MSZ * 2);    // weight bf16 [kw][kh][cout][cin]
  float* buf0 = (float*)alloc((size_t)5 * MSZ * 4);
  float* buf1 = (float*)alloc((size_t)5 * MSZ * 4);
  float* T = (float*)alloc((size_t)5 * MSZ * 4);
  float* At = (float*)alloc((size_t)5 * MSZ * 4);
  float* PQ = (float*)alloc((size_t)4 * MSZ * 4);
  float* C12 = (float*)alloc((size_t)2 * MSZ * 4);
  float* P = (float*)alloc((size_t)4 * MSZ * 4);
  float* Q = (float*)alloc((size_t)4 * MSZ * 4);
  float* R = (float*)alloc((size_t)9 * MSZ * 4);
  float* sval = (float*)alloc(256);
  (void)in_sizes; (void)n_in; (void)out_size; (void)ws_size;

  convert_k<<<32768, 256, 0, stream>>>(x, xb);
  transpose_k<<<dim3(64, 5), 256, 0, stream>>>(param, At);
  power_k<<<5, 256, 0, stream>>>(param, At, u0, buf0, sval);
  float* cur = buf0;
  float* nxt = buf1;
  for (int t = 0; t < 20; ++t) {
    wtw_k<<<dim3(64, 5), 256, 0, stream>>>(cur, T);
    update_k<<<dim3(64, 5), 256, 0, stream>>>(cur, T, nxt);
    float* tmp = cur; cur = nxt; nxt = tmp;
  }
  // after even # of swaps, cur == buf0 holds the orthogonalized matrices
  pq_k<<<dim3(64, 4), 256, 0, stream>>>(cur, PQ);
  c12_k<<<dim3(64, 2), 256, 0, stream>>>(PQ, C12);
  blocks_k<<<256, 256, 0, stream>>>(PQ, C12, P, Q);
  mconv_k<<<dim3(64, 9), 256, 0, stream>>>(P, Q, R);
  final_k<<<dim3(64, 9), 256, 0, stream>>>(cur, R, Wb);
  conv_k<<<2048, 256, 0, stream>>>(xb, Wb, bias, out);
}